// Round 6
// baseline (149.637 us; speedup 1.0000x reference)
//
#include <hip/hip_runtime.h>

// Where2comm AttenFusion, ego-row-only. R2 structure + per-block sequential
// chunk loop (contiguous-span blocks, within-CU boundary-line reuse).
// x: (B=16, N=5, C=64, HW=25200) f32; out: (B, C, HW) f32.
// Per pixel p: dot[m] = <x[b,0,:,p], x[b,m,:,p]>/8; w = softmax(dot);
// out[b,:,p] = sum_m w[m]*x[b,m,:,p].
//
// Why the loop: plane stride 100800 B == 64 (mod 128), so odd-channel planes
// start mid-L2-line. A 64-px chunk's 256B-per-plane read run straddles two
// half-used 128B boundary lines. With one chunk per block (R2), the other
// halves are fetched by DIFFERENT blocks on other XCDs (~1.25x read
// amplification if L3 doesn't absorb it). Here each block walks 6-7
// CONSECUTIVE chunks, so boundary lines are re-touched by the same CU a few
// microseconds later -> guaranteed cache hit. Residual waste ~4% (block
// edges only). No swizzle (R5 showed footprint dispersal hurts), no LDS.

#define B_ 16
#define N_ 5
#define C_ 64
#define HW_ 25200
#define PG_PER_IMG (HW_ / 4)   // 6300 pixel-quads per image
#define CHUNKS 6300            // total 64-px chunks (16 quads each)
#define NBLK 1024
#define QCH (CHUNKS / NBLK)    // 6
#define RCH (CHUNKS % NBLK)    // 156

typedef float f4 __attribute__((ext_vector_type(4)));

__global__ __launch_bounds__(256) void where2comm_atten_kernel(
    const float* __restrict__ x, float* __restrict__ out)
{
    const int bid = blockIdx.x;
    // contiguous chunk range for this block: first RCH blocks get QCH+1
    const int cbeg = bid * QCH + (bid < RCH ? bid : RCH);
    const int cend = cbeg + QCH + (bid < RCH ? 1 : 0);

    const int t   = threadIdx.x;
    const int l   = t & 63;
    const int sub = (t >> 6) * 4 + (l & 3);   // quad index within chunk, 0..15
    const int cl  = l >> 2;                   // chan-lane 0..15

    for (int ch = cbeg; ch < cend; ++ch) {
        const int pg = ch * 16 + sub;             // global 4-pixel group
        const int b  = pg / PG_PER_IMG;
        const int p  = (pg - b * PG_PER_IMG) * 4; // pixel offset in image

        const float* xb = x + (size_t)b * (N_ * C_ * HW_)
                            + (size_t)(cl * 4) * HW_ + p;

        // Load 5 cavs x 4 channels x 4 pixels, all dwordx4.
        f4 v[N_][4];
#pragma unroll
        for (int m = 0; m < N_; ++m)
#pragma unroll
            for (int j = 0; j < 4; ++j)
                v[m][j] = *reinterpret_cast<const f4*>(xb + (size_t)(m * C_ + j) * HW_);

        // Per-pixel partial dots over this lane's 4 channels.
        f4 d[N_];
#pragma unroll
        for (int m = 0; m < N_; ++m) {
            f4 acc = v[0][0] * v[m][0];
#pragma unroll
            for (int j = 1; j < 4; ++j) acc += v[0][j] * v[m][j];
            d[m] = acc;
        }

        // Reduce across the 16 chan-lanes (lane stride 4): masks 4,8,16,32.
#pragma unroll
        for (int mask = 4; mask <= 32; mask <<= 1)
#pragma unroll
            for (int m = 0; m < N_; ++m)
#pragma unroll
                for (int c = 0; c < 4; ++c)
                    d[m][c] += __shfl_xor(d[m][c], mask);

        // Softmax over the 5 cavs, per pixel component.
        f4 wgt[N_];
#pragma unroll
        for (int c = 0; c < 4; ++c) {
            float dd[N_];
#pragma unroll
            for (int m = 0; m < N_; ++m) dd[m] = d[m][c] * 0.125f;  // / sqrt(64)
            float mx = dd[0];
#pragma unroll
            for (int m = 1; m < N_; ++m) mx = fmaxf(mx, dd[m]);
            float s = 0.f;
#pragma unroll
            for (int m = 0; m < N_; ++m) { dd[m] = __expf(dd[m] - mx); s += dd[m]; }
            const float inv = 1.0f / s;
#pragma unroll
            for (int m = 0; m < N_; ++m) wgt[m][c] = dd[m] * inv;
        }

        // out[b, cl*4+j, p..p+3] = sum_m wgt[m] * v[m][j]
        float* ob = out + (size_t)b * (C_ * HW_) + (size_t)(cl * 4) * HW_ + p;
#pragma unroll
        for (int j = 0; j < 4; ++j) {
            f4 a = wgt[0] * v[0][j];
#pragma unroll
            for (int m = 1; m < N_; ++m) a += wgt[m] * v[m][j];
            *reinterpret_cast<f4*>(ob + (size_t)j * HW_) = a;
        }
    }
}

extern "C" void kernel_launch(void* const* d_in, const int* in_sizes, int n_in,
                              void* d_out, int out_size, void* d_ws, size_t ws_size,
                              hipStream_t stream) {
    const float* x = (const float*)d_in[0];
    float* out = (float*)d_out;
    where2comm_atten_kernel<<<NBLK, 256, 0, stream>>>(x, out);
}

// Round 7
// 142.188 us; speedup vs baseline: 1.0524x; 1.0524x over previous
//
#include <hip/hip_runtime.h>

// Where2comm AttenFusion, ego-row-only. R2 per-wave structure, 1024-thread
// blocks (16 parallel waves -> 1KB contiguous footprint per plane per block).
// x: (B=16, N=5, C=64, HW=25200) f32; out: (B, C, HW) f32.
// Per pixel p: dot[m] = <x[b,0,:,p], x[b,m,:,p]>/8; w = softmax(dot);
// out[b,:,p] = sum_m w[m]*x[b,m,:,p].
//
// Why 1024 threads: traffic is set by the BLOCK-level footprint (R2 vs R4:
// same 256B/plane footprint, same perf despite 4x different run length).
// Plane stride 100800 B == 64 (mod 128): a 256B/plane footprint straddles
// 3 L2 lines on odd planes (1.25x read amplification) and touches 320 pages
// at only 256B each. 1KB/plane cuts amplification to 1.0625x and quadruples
// bytes-per-page-touch. All 16 waves parallel (no R6 serialization), default
// dispatch (no R5 dispersal). launch_bounds(1024) forces <=128 VGPR so the
// 16-wave block is schedulable (data = 80 VGPRs, ~115 total, no spill).

#define B_ 16
#define N_ 5
#define C_ 64
#define HW_ 25200
#define PG_PER_IMG (HW_ / 4)   // 6300 quads/image
#define NBLK ((B_ * PG_PER_IMG) / 64)  // 100800 quads / 64 per block = 1575

typedef float f4 __attribute__((ext_vector_type(4)));

__global__ __launch_bounds__(1024) void where2comm_atten_kernel(
    const float* __restrict__ x, float* __restrict__ out)
{
    const int t   = threadIdx.x;
    const int wv  = t >> 6;                    // wave 0..15
    const int l   = t & 63;
    const int pg  = blockIdx.x * 64 + wv * 4 + (l & 3);  // global 4-pixel group
    const int cl  = l >> 2;                    // chan-lane 0..15
    const int b   = pg / PG_PER_IMG;
    const int p   = (pg - b * PG_PER_IMG) * 4; // pixel offset in image

    const float* xb = x + (size_t)b * (N_ * C_ * HW_) + (size_t)(cl * 4) * HW_ + p;

    // Load 5 cavs x 4 channels x 4 pixels, all dwordx4.
    f4 v[N_][4];
#pragma unroll
    for (int m = 0; m < N_; ++m)
#pragma unroll
        for (int j = 0; j < 4; ++j)
            v[m][j] = *reinterpret_cast<const f4*>(xb + (size_t)(m * C_ + j) * HW_);

    // Per-pixel partial dots over this lane's 4 channels.
    f4 d[N_];
#pragma unroll
    for (int m = 0; m < N_; ++m) {
        f4 acc = v[0][0] * v[m][0];
#pragma unroll
        for (int j = 1; j < 4; ++j) acc += v[0][j] * v[m][j];
        d[m] = acc;
    }

    // Reduce across the 16 chan-lanes (lane stride 4): masks 4,8,16,32.
#pragma unroll
    for (int mask = 4; mask <= 32; mask <<= 1)
#pragma unroll
        for (int m = 0; m < N_; ++m)
#pragma unroll
            for (int c = 0; c < 4; ++c)
                d[m][c] += __shfl_xor(d[m][c], mask);

    // Softmax over the 5 cavs, per pixel component.
    f4 wgt[N_];
#pragma unroll
    for (int c = 0; c < 4; ++c) {
        float dd[N_];
#pragma unroll
        for (int m = 0; m < N_; ++m) dd[m] = d[m][c] * 0.125f;  // / sqrt(64)
        float mx = dd[0];
#pragma unroll
        for (int m = 1; m < N_; ++m) mx = fmaxf(mx, dd[m]);
        float s = 0.f;
#pragma unroll
        for (int m = 0; m < N_; ++m) { dd[m] = __expf(dd[m] - mx); s += dd[m]; }
        const float inv = 1.0f / s;
#pragma unroll
        for (int m = 0; m < N_; ++m) wgt[m][c] = dd[m] * inv;
    }

    // out[b, cl*4+j, p..p+3] = sum_m wgt[m] * v[m][j]
    float* ob = out + (size_t)b * (C_ * HW_) + (size_t)(cl * 4) * HW_ + p;
#pragma unroll
    for (int j = 0; j < 4; ++j) {
        f4 a = wgt[0] * v[0][j];
#pragma unroll
        for (int m = 1; m < N_; ++m) a += wgt[m] * v[m][j];
        *reinterpret_cast<f4*>(ob + (size_t)j * HW_) = a;
    }
}

extern "C" void kernel_launch(void* const* d_in, const int* in_sizes, int n_in,
                              void* d_out, int out_size, void* d_ws, size_t ws_size,
                              hipStream_t stream) {
    const float* x = (const float*)d_in[0];
    float* out = (float*)d_out;
    where2comm_atten_kernel<<<NBLK, 1024, 0, stream>>>(x, out);
}

// Round 8
// 124.813 us; speedup vs baseline: 1.1989x; 1.1392x over previous
//
#include <hip/hip_runtime.h>

// Where2comm AttenFusion, ego-row-only, float4-over-pixels version (R2 — best).
// x: (B=16, N=5, C=64, HW=25200) f32; out: (B, C, HW) f32.
// Per pixel p: dot[m] = <x[b,0,:,p], x[b,m,:,p]>/8; w = softmax(dot);
// out[b,:,p] = sum_m w[m]*x[b,m,:,p].
//
// Final structure (all alternatives measured worse):
//   - each lane owns 4 consecutive pixels x 4 channels x 5 cavs (f4 loads,
//     80 data VGPRs, fully register-resident, single pass)
//   - lane map: l&3 = pixel-group (4 lanes x 16B = 64B run per plane),
//     l>>2 = chan-lane; dot reduced with shfl_xor {4,8,16,32}
//   - 256-thread blocks, default dispatch order, no LDS, no nt hints
// Measured 124.6 us = 4.97 TB/s effective on the minimal 619 MB traffic
// (79% of copy ceiling). Falsified levers: nt (-16%), XCD swizzle (-9%),
// sequential chunks (-20%), 1024-thread footprint (-14%), 256B runs / LDS
// cross-wave reduce (neutral). Remaining gap is the channel-planar layout's
// 21-stream, stride==64-mod-128 pattern — not addressable at source level.

#define B_ 16
#define N_ 5
#define C_ 64
#define HW_ 25200
#define PG_PER_IMG (HW_ / 4)   // 6300, divisible by 4 -> wave never straddles b

typedef float f4 __attribute__((ext_vector_type(4)));

__global__ __launch_bounds__(256) void where2comm_atten_kernel(
    const float* __restrict__ x, float* __restrict__ out)
{
    const int tid = blockIdx.x * 256 + threadIdx.x;
    const int l   = tid & 63;
    const int pg  = (tid >> 6) * 4 + (l & 3);   // global 4-pixel group
    const int cl  = l >> 2;                     // chan-lane 0..15
    const int b   = pg / PG_PER_IMG;
    const int p   = (pg - b * PG_PER_IMG) * 4;  // pixel offset in image (16B-aligned)

    const float* xb = x + (size_t)b * (N_ * C_ * HW_) + (size_t)(cl * 4) * HW_ + p;

    // Load 5 cavs x 4 channels x 4 pixels, all dwordx4.
    f4 v[N_][4];
#pragma unroll
    for (int m = 0; m < N_; ++m)
#pragma unroll
        for (int j = 0; j < 4; ++j)
            v[m][j] = *reinterpret_cast<const f4*>(xb + (size_t)(m * C_ + j) * HW_);

    // Per-pixel partial dots over this lane's 4 channels.
    f4 d[N_];
#pragma unroll
    for (int m = 0; m < N_; ++m) {
        f4 acc = v[0][0] * v[m][0];
#pragma unroll
        for (int j = 1; j < 4; ++j) acc += v[0][j] * v[m][j];
        d[m] = acc;
    }

    // Reduce across the 16 chan-lanes (lane stride 4): masks 4,8,16,32.
#pragma unroll
    for (int mask = 4; mask <= 32; mask <<= 1)
#pragma unroll
        for (int m = 0; m < N_; ++m)
#pragma unroll
            for (int c = 0; c < 4; ++c)
                d[m][c] += __shfl_xor(d[m][c], mask);

    // Softmax over the 5 cavs, per pixel component.
    f4 wgt[N_];
#pragma unroll
    for (int c = 0; c < 4; ++c) {
        float dd[N_];
#pragma unroll
        for (int m = 0; m < N_; ++m) dd[m] = d[m][c] * 0.125f;  // / sqrt(64)
        float mx = dd[0];
#pragma unroll
        for (int m = 1; m < N_; ++m) mx = fmaxf(mx, dd[m]);
        float s = 0.f;
#pragma unroll
        for (int m = 0; m < N_; ++m) { dd[m] = __expf(dd[m] - mx); s += dd[m]; }
        const float inv = 1.0f / s;
#pragma unroll
        for (int m = 0; m < N_; ++m) wgt[m][c] = dd[m] * inv;
    }

    // out[b, cl*4+j, p..p+3] = sum_m wgt[m] * v[m][j]
    float* ob = out + (size_t)b * (C_ * HW_) + (size_t)(cl * 4) * HW_ + p;
#pragma unroll
    for (int j = 0; j < 4; ++j) {
        f4 a = wgt[0] * v[0][j];
#pragma unroll
        for (int m = 1; m < N_; ++m) a += wgt[m] * v[m][j];
        *reinterpret_cast<f4*>(ob + (size_t)j * HW_) = a;
    }
}

extern "C" void kernel_launch(void* const* d_in, const int* in_sizes, int n_in,
                              void* d_out, int out_size, void* d_ws, size_t ws_size,
                              hipStream_t stream) {
    const float* x = (const float*)d_in[0];
    float* out = (float*)d_out;
    // threads = B*HW/4 groups * 16 lanes = 1,612,800 = 6300 blocks of 256 exactly
    const int blocks = (B_ * HW_ / 4 * 16) / 256;
    where2comm_atten_kernel<<<blocks, 256, 0, stream>>>(x, out);
}